// Round 3
// baseline (336.467 us; speedup 1.0000x reference)
//
#include <hip/hip_runtime.h>

#define N_SAMP 8192
#define D_DIM 6144
#define K_CLS 10
#define CHUNK 32
#define NWIN (N_SAMP / CHUNK)             // 256 windows, always full
#define COLS_PER_BLOCK 1024               // 256 threads * 4 floats
#define NGROUPS (D_DIM / COLS_PER_BLOCK)  // 6  -> grid 1536 = 6 blocks/CU even
#define NBLK (NGROUPS * NWIN)             // 1536 accum blocks
#define PIPE 8                            // outstanding float4 loads per thread

typedef float f4 __attribute__((ext_vector_type(4)));

// Device-scope (agent) relaxed atomics: executed at the device coherence
// point; never dirty a per-XCD L2, so no fences/writebacks needed anywhere.
__device__ __forceinline__ void atom_add_dev(float* p, float v) {
    __hip_atomic_fetch_add(p, v, __ATOMIC_RELAXED, __HIP_MEMORY_SCOPE_AGENT);
}
__device__ __forceinline__ float load_dev(const float* p) {
    return __hip_atomic_load(p, __ATOMIC_RELAXED, __HIP_MEMORY_SCOPE_AGENT);
}
__device__ __forceinline__ float wave_sum(float x) {
#pragma unroll
    for (int o = 32; o > 0; o >>= 1) x += __shfl_down(x, o, 64);
    return x;
}

// Kernel A: 1024-thread atomic-free counting sort by class, with fused
// zero-init of S1/s2sum/ctr. sorted[] packs (class<<16 | idx). counts[k] out.
__global__ __launch_bounds__(1024) void build_sort(const int* __restrict__ y,
                                                   int* __restrict__ counts,
                                                   int* __restrict__ sorted,
                                                   float* __restrict__ S1,
                                                   float* __restrict__ s2sum,
                                                   unsigned* __restrict__ ctr) {
    __shared__ int M[K_CLS * 1024];
    __shared__ int wsum[16];
    const int tid = threadIdx.x;
    const int lane = tid & 63;
    const int wid = tid >> 6;

    // ---- fused zero-init: S1 (61440 f) + s2sum (10 f) + arrival ctr ----
    {
        f4 z = {0.f, 0.f, 0.f, 0.f};
        f4* p = (f4*)S1;
#pragma unroll
        for (int i = 0; i < (K_CLS * D_DIM) / (4 * 1024); ++i)  // 15 per thread
            p[i * 1024 + tid] = z;
        if (tid < K_CLS) s2sum[tid] = 0.f;
        if (tid == K_CLS) *ctr = 0u;
    }

    // per-thread histogram over 8 contiguous labels (int4 loads)
    const int base = tid * 8;
    const int4 ya = ((const int4*)y)[tid * 2];
    const int4 yb = ((const int4*)y)[tid * 2 + 1];
    int yy[8] = {ya.x, ya.y, ya.z, ya.w, yb.x, yb.y, yb.z, yb.w};
    int h[K_CLS];
#pragma unroll
    for (int k = 0; k < K_CLS; ++k) h[k] = 0;
#pragma unroll
    for (int i = 0; i < 8; ++i)
#pragma unroll
        for (int k = 0; k < K_CLS; ++k) h[k] += (yy[i] == k) ? 1 : 0;
#pragma unroll
    for (int k = 0; k < K_CLS; ++k) M[k * 1024 + tid] = h[k];
    __syncthreads();

    // block exclusive scan over M flat [10240], class-major
    int loc[K_CLS];
    int run = 0;
#pragma unroll
    for (int j = 0; j < K_CLS; ++j) { loc[j] = run; run += M[tid * K_CLS + j]; }
    int v = run;
#pragma unroll
    for (int d = 1; d < 64; d <<= 1) {
        int n = __shfl_up(v, d, 64);
        if (lane >= d) v += n;
    }
    if (lane == 63) wsum[wid] = v;
    __syncthreads();
    int wbase = 0;
#pragma unroll
    for (int w = 0; w < 16; ++w) wbase += (w < wid) ? wsum[w] : 0;
    const int tbase = wbase + (v - run);
    __syncthreads();
#pragma unroll
    for (int j = 0; j < K_CLS; ++j) M[tid * K_CLS + j] = tbase + loc[j];
    __syncthreads();

    if (tid < K_CLS) {
        const int s = M[tid * 1024];
        const int e = (tid == K_CLS - 1) ? N_SAMP : M[(tid + 1) * 1024];
        counts[tid] = e - s;
    }

    // stable scatter, class packed in high bits
    int off[K_CLS];
#pragma unroll
    for (int k = 0; k < K_CLS; ++k) off[k] = M[k * 1024 + tid];
#pragma unroll
    for (int i = 0; i < 8; ++i)
#pragma unroll
        for (int k = 0; k < K_CLS; ++k)
            if (yy[i] == k) sorted[off[k]++] = (k << 16) | (base + i);
}

// Kernel B: one block = one 32-sample sorted window x one 1024-col slice.
// r1/r2 post-mortem: VGPR_Count=32 proved the old f4 buf[8] pipeline lived in
// SCRATCH (runtime-indexed array, loop not unrolled past the barrier branch;
// rule #20) -> every X value round-tripped through scratch, ~1.3 TB/s.
// Now: hand-unrolled 32 steps with NAMED registers q0..q7 (nothing the
// compiler can demote), zero barriers/LDS in the body (boundary flush is a
// per-wave shuffle-reduce + lane0 device-scope atomic; block-uniform scalar
// branch), scalarized row offsets -> saddr-form loads.
__global__ __launch_bounds__(256, 6) void wcss_accum(const float* __restrict__ X,
                                                     const int* __restrict__ sorted,
                                                     const int* __restrict__ counts,
                                                     float* __restrict__ S1,
                                                     float* __restrict__ s2sum,
                                                     unsigned* __restrict__ ctr,
                                                     float* __restrict__ out) {
    __shared__ int off_lds[CHUNK];   // row byte-offsets (wave-uniform values)
    __shared__ int cls_lds[CHUNK];
    __shared__ float wred[4];
    __shared__ int last_s;
    const int tid = threadIdx.x;
    const int lane = tid & 63;
    const int wid = tid >> 6;
    const int col0 = blockIdx.x * COLS_PER_BLOCK + tid * 4;

    if (tid < CHUNK) {
        const int p = sorted[blockIdx.y * CHUNK + tid];
        off_lds[tid] = (p & 0xffff) * (D_DIM * (int)sizeof(float));
        cls_lds[tid] = p >> 16;
    }
    __syncthreads();

    const char* basep = (const char*)(X + col0);
    f4 a1 = {0.f, 0.f, 0.f, 0.f};
    float s2c = 0.f;
    int kcur = __builtin_amdgcn_readfirstlane(cls_lds[0]);

    // row load: SGPR row-offset + per-thread column offset -> saddr form
#define LOADROW(r) (*(const f4*)(basep + \
        (size_t)__builtin_amdgcn_readfirstlane(off_lds[(r)])))

    f4 q0 = LOADROW(0), q1 = LOADROW(1), q2 = LOADROW(2), q3 = LOADROW(3);
    f4 q4 = LOADROW(4), q5 = LOADROW(5), q6 = LOADROW(6), q7 = LOADROW(7);

#define STEP(S, Q)                                                          \
    {                                                                       \
        const f4 v = Q;                                                     \
        if ((S) + PIPE < CHUNK) Q = LOADROW((S) + PIPE);                    \
        const int yk = __builtin_amdgcn_readfirstlane(cls_lds[(S)]);        \
        if (yk != kcur) { /* block-uniform scalar branch, rare */           \
            float* p1 = S1 + kcur * D_DIM + col0;                           \
            atom_add_dev(p1 + 0, a1.x); atom_add_dev(p1 + 1, a1.y);         \
            atom_add_dev(p1 + 2, a1.z); atom_add_dev(p1 + 3, a1.w);         \
            float r_ = wave_sum(s2c);                                       \
            if (lane == 0) atom_add_dev(&s2sum[kcur], r_);                  \
            a1 = (f4){0.f, 0.f, 0.f, 0.f};                                  \
            s2c = 0.f;                                                      \
            kcur = yk;                                                      \
        }                                                                   \
        a1 += v;                                                            \
        s2c += v.x * v.x + v.y * v.y + v.z * v.z + v.w * v.w;               \
    }

    STEP(0, q0)  STEP(1, q1)  STEP(2, q2)  STEP(3, q3)
    STEP(4, q4)  STEP(5, q5)  STEP(6, q6)  STEP(7, q7)
    STEP(8, q0)  STEP(9, q1)  STEP(10, q2) STEP(11, q3)
    STEP(12, q4) STEP(13, q5) STEP(14, q6) STEP(15, q7)
    STEP(16, q0) STEP(17, q1) STEP(18, q2) STEP(19, q3)
    STEP(20, q4) STEP(21, q5) STEP(22, q6) STEP(23, q7)
    STEP(24, q0) STEP(25, q1) STEP(26, q2) STEP(27, q3)
    STEP(28, q4) STEP(29, q5) STEP(30, q6) STEP(31, q7)
#undef STEP
#undef LOADROW

    // final flush (per-wave, no LDS)
    float* p1 = S1 + kcur * D_DIM + col0;
    atom_add_dev(p1 + 0, a1.x); atom_add_dev(p1 + 1, a1.y);
    atom_add_dev(p1 + 2, a1.z); atom_add_dev(p1 + 3, a1.w);
    float rw = wave_sum(s2c);
    if (lane == 0) atom_add_dev(&s2sum[kcur], rw);

    // my wave's device-scope atomics are complete at the coherence point:
    asm volatile("s_waitcnt vmcnt(0)" ::: "memory");
    __syncthreads();        // => ALL waves of this block completed theirs
    if (tid == 0) {
        unsigned t = __hip_atomic_fetch_add(ctr, 1u, __ATOMIC_RELAXED,
                                            __HIP_MEMORY_SCOPE_AGENT);
        last_s = (t == (unsigned)(NBLK - 1)) ? 1 : 0;
    }
    __syncthreads();
    if (!last_s) return;

    // ---- last-block fused finish (agent-scope loads bypass stale caches) ---
    // total = sum_k [ s2sum_k/(c_k*D*K) - sum_col S1[k,col]^2/(c_k^2*D*K) ]
    float part = 0.f;
#pragma unroll
    for (int k = 0; k < K_CLS; ++k) {
        const float c = (float)counts[k];
        const float inv2 = 1.0f / (c * c * (float)D_DIM * (float)K_CLS);
        const float* Sk = S1 + k * D_DIM;
        for (int j = 0; j < D_DIM / 256; ++j) {    // 24 coalesced agent loads
            float vv = load_dev(&Sk[j * 256 + tid]);
            part -= vv * vv * inv2;
        }
        if (tid == 0)
            part += load_dev(&s2sum[k]) / (c * (float)D_DIM * (float)K_CLS);
    }
    float r = wave_sum(part);
    if (lane == 0) wred[wid] = r;
    __syncthreads();
    if (tid == 0) *out = wred[0] + wred[1] + wred[2] + wred[3];
}

extern "C" void kernel_launch(void* const* d_in, const int* in_sizes, int n_in,
                              void* d_out, int out_size, void* d_ws, size_t ws_size,
                              hipStream_t stream) {
    const float* X = (const float*)d_in[0];
    const int* y = (const int*)d_in[1];

    float* S1 = (float*)d_ws;                       // K*D floats
    float* s2sum = S1 + K_CLS * D_DIM;              // K floats
    int* counts = (int*)(s2sum + K_CLS);            // K ints
    int* sorted = counts + K_CLS;                   // N ints
    unsigned* ctr = (unsigned*)(sorted + N_SAMP);   // 1 uint (arrival ticket)
    float* out = (float*)d_out;

    // 2 dispatches total.
    build_sort<<<dim3(1), dim3(1024), 0, stream>>>(y, counts, sorted,
                                                   S1, s2sum, ctr);
    wcss_accum<<<dim3(NGROUPS, NWIN), dim3(256), 0, stream>>>(X, sorted, counts,
                                                              S1, s2sum, ctr, out);
}

// Round 4
// 332.583 us; speedup vs baseline: 1.0117x; 1.0117x over previous
//
#include <hip/hip_runtime.h>

#define N_SAMP 8192
#define D_DIM 6144
#define K_CLS 10
#define CHUNK 32
#define NWIN (N_SAMP / CHUNK)             // 256 windows, always full
#define COLS_PER_BLOCK 1024               // 256 threads * 4 floats
#define NGROUPS (D_DIM / COLS_PER_BLOCK)  // 6  -> grid 1536 = 6 blocks/CU even
#define NBLK (NGROUPS * NWIN)             // 1536 accum blocks

typedef float f4 __attribute__((ext_vector_type(4)));

// Device-scope (agent) relaxed atomics: execute at the device coherence point;
// never dirty a per-XCD L2, no fences needed. (r1 lesson: per-block agent
// fences = buffer_wbl2/inv = 3.5x. r3 lesson: WRITE_SIZE ~25MB is atomic
// writeback bytes, present with or without fences -- benign.)
__device__ __forceinline__ void atom_add_dev(float* p, float v) {
    __hip_atomic_fetch_add(p, v, __ATOMIC_RELAXED, __HIP_MEMORY_SCOPE_AGENT);
}
__device__ __forceinline__ float load_dev(const float* p) {
    return __hip_atomic_load(p, __ATOMIC_RELAXED, __HIP_MEMORY_SCOPE_AGENT);
}
__device__ __forceinline__ float wave_sum(float x) {
#pragma unroll
    for (int o = 32; o > 0; o >>= 1) x += __shfl_down(x, o, 64);
    return x;
}

// Kernel A: 1024-thread atomic-free counting sort by class, with fused
// zero-init of S1/s2sum/ctr. sorted[] packs (class<<16 | idx). counts[k] out.
__global__ __launch_bounds__(1024) void build_sort(const int* __restrict__ y,
                                                   int* __restrict__ counts,
                                                   int* __restrict__ sorted,
                                                   float* __restrict__ S1,
                                                   float* __restrict__ s2sum,
                                                   unsigned* __restrict__ ctr) {
    __shared__ int M[K_CLS * 1024];
    __shared__ int wsum[16];
    const int tid = threadIdx.x;
    const int lane = tid & 63;
    const int wid = tid >> 6;

    // ---- fused zero-init: S1 (61440 f) + s2sum (10 f) + arrival ctr ----
    {
        f4 z = {0.f, 0.f, 0.f, 0.f};
        f4* p = (f4*)S1;
#pragma unroll
        for (int i = 0; i < (K_CLS * D_DIM) / (4 * 1024); ++i)  // 15 per thread
            p[i * 1024 + tid] = z;
        if (tid < K_CLS) s2sum[tid] = 0.f;
        if (tid == K_CLS) *ctr = 0u;
    }

    // per-thread histogram over 8 contiguous labels (int4 loads)
    const int base = tid * 8;
    const int4 ya = ((const int4*)y)[tid * 2];
    const int4 yb = ((const int4*)y)[tid * 2 + 1];
    int yy[8] = {ya.x, ya.y, ya.z, ya.w, yb.x, yb.y, yb.z, yb.w};
    int h[K_CLS];
#pragma unroll
    for (int k = 0; k < K_CLS; ++k) h[k] = 0;
#pragma unroll
    for (int i = 0; i < 8; ++i)
#pragma unroll
        for (int k = 0; k < K_CLS; ++k) h[k] += (yy[i] == k) ? 1 : 0;
#pragma unroll
    for (int k = 0; k < K_CLS; ++k) M[k * 1024 + tid] = h[k];
    __syncthreads();

    // block exclusive scan over M flat [10240], class-major
    int loc[K_CLS];
    int run = 0;
#pragma unroll
    for (int j = 0; j < K_CLS; ++j) { loc[j] = run; run += M[tid * K_CLS + j]; }
    int v = run;
#pragma unroll
    for (int d = 1; d < 64; d <<= 1) {
        int n = __shfl_up(v, d, 64);
        if (lane >= d) v += n;
    }
    if (lane == 63) wsum[wid] = v;
    __syncthreads();
    int wbase = 0;
#pragma unroll
    for (int w = 0; w < 16; ++w) wbase += (w < wid) ? wsum[w] : 0;
    const int tbase = wbase + (v - run);
    __syncthreads();
#pragma unroll
    for (int j = 0; j < K_CLS; ++j) M[tid * K_CLS + j] = tbase + loc[j];
    __syncthreads();

    if (tid < K_CLS) {
        const int s = M[tid * 1024];
        const int e = (tid == K_CLS - 1) ? N_SAMP : M[(tid + 1) * 1024];
        counts[tid] = e - s;
    }

    // stable scatter, class packed in high bits
    int off[K_CLS];
#pragma unroll
    for (int k = 0; k < K_CLS; ++k) off[k] = M[k * 1024 + tid];
#pragma unroll
    for (int i = 0; i < 8; ++i)
#pragma unroll
        for (int k = 0; k < K_CLS; ++k)
            if (yy[i] == k) sorted[off[k]++] = (k << 16) | (base + i);
}

// Kernel B: one block = one 32-sample sorted window x one 1024-col slice.
// r3 post-mortem: VGPR_Count=32 proved the compiler SANK the prefetch loads
// to their uses (legal for plain loads) -> 1-deep pipeline, latency-bound at
// 1.6 TB/s. Fix: 3-bank x 4-row batch pipeline where each batch is PINNED by
// an empty asm that (a) READS the 4 loaded f4s -> compiler must emit a
// counted s_waitcnt vmcnt(N) there, (b) clobbers "memory" -> no load may
// sink past it. Sustained 8-12 KB MLP/wave x 24 waves/CU >> ~20 KB needed
// for HBM saturation. All 32 window words hoisted to SGPRs once
// (readfirstlane of broadcast loads): no LDS/barriers/ds_read in the loop,
// class checks are scalar compares.
__global__ __launch_bounds__(256, 6) void wcss_accum(const float* __restrict__ X,
                                                     const int* __restrict__ sorted,
                                                     const int* __restrict__ counts,
                                                     float* __restrict__ S1,
                                                     float* __restrict__ s2sum,
                                                     unsigned* __restrict__ ctr,
                                                     float* __restrict__ out) {
    __shared__ float wred[4];
    __shared__ int last_s;
    const int tid = threadIdx.x;
    const int lane = tid & 63;
    const int wid = tid >> 6;
    const int col0 = blockIdx.x * COLS_PER_BLOCK + tid * 4;

    // all 32 packed window words -> SGPRs (uniform broadcast loads)
    const int* wp = sorted + blockIdx.y * CHUNK;
    int w[CHUNK];
#pragma unroll
    for (int r = 0; r < CHUNK; ++r)
        w[r] = __builtin_amdgcn_readfirstlane(wp[r]);

    const char* xb = (const char*)X + (size_t)col0 * 4;
#define LOADR(r) (*(const f4*)(xb + \
        (size_t)(unsigned)((w[(r)] & 0xffff) * (D_DIM * 4))))

    f4 a1 = {0.f, 0.f, 0.f, 0.f};
    float s2c = 0.f;
    int kcur = w[0] >> 16;

    f4 qa0, qa1, qa2, qa3, qb0, qb1, qb2, qb3, qc0, qc1, qc2, qc3;

#define ISSUE(Q, b) { Q##0 = LOADR(4*(b)+0); Q##1 = LOADR(4*(b)+1); \
                      Q##2 = LOADR(4*(b)+2); Q##3 = LOADR(4*(b)+3); }
    // Pin: forces counted vmcnt wait HERE and forbids sinking loads past it.
#define PIN(Q) asm volatile("" :: "v"(Q##0), "v"(Q##1), "v"(Q##2), "v"(Q##3) \
                            : "memory")
#define EAT1(r, V) { \
        const int yk = w[(r)] >> 16; \
        if (yk != kcur) { /* scalar branch, rare (<=9 windows of 256) */ \
            float* p1 = S1 + kcur * D_DIM + col0; \
            atom_add_dev(p1 + 0, a1.x); atom_add_dev(p1 + 1, a1.y); \
            atom_add_dev(p1 + 2, a1.z); atom_add_dev(p1 + 3, a1.w); \
            float r_ = wave_sum(s2c); \
            if (lane == 0) atom_add_dev(&s2sum[kcur], r_); \
            a1 = (f4){0.f, 0.f, 0.f, 0.f}; s2c = 0.f; kcur = yk; } \
        a1 += V; \
        s2c += V.x * V.x + V.y * V.y + V.z * V.z + V.w * V.w; }
#define EAT4(b, Q) { EAT1(4*(b)+0, Q##0) EAT1(4*(b)+1, Q##1) \
                     EAT1(4*(b)+2, Q##2) EAT1(4*(b)+3, Q##3) }

    ISSUE(qa, 0) ISSUE(qb, 1) ISSUE(qc, 2)        // 12 loads in flight
    PIN(qa); EAT4(0, qa) ISSUE(qa, 3)
    PIN(qb); EAT4(1, qb) ISSUE(qb, 4)
    PIN(qc); EAT4(2, qc) ISSUE(qc, 5)
    PIN(qa); EAT4(3, qa) ISSUE(qa, 6)
    PIN(qb); EAT4(4, qb) ISSUE(qb, 7)
    PIN(qc); EAT4(5, qc)
    PIN(qa); EAT4(6, qa)
    PIN(qb); EAT4(7, qb)
#undef EAT4
#undef EAT1
#undef PIN
#undef ISSUE
#undef LOADR

    // final flush (per-wave, no LDS)
    float* p1 = S1 + kcur * D_DIM + col0;
    atom_add_dev(p1 + 0, a1.x); atom_add_dev(p1 + 1, a1.y);
    atom_add_dev(p1 + 2, a1.z); atom_add_dev(p1 + 3, a1.w);
    float rw = wave_sum(s2c);
    if (lane == 0) atom_add_dev(&s2sum[kcur], rw);

    // my wave's device-scope atomics are complete at the coherence point:
    asm volatile("s_waitcnt vmcnt(0)" ::: "memory");
    __syncthreads();        // => ALL waves of this block completed theirs
    if (tid == 0) {
        unsigned t = __hip_atomic_fetch_add(ctr, 1u, __ATOMIC_RELAXED,
                                            __HIP_MEMORY_SCOPE_AGENT);
        last_s = (t == (unsigned)(NBLK - 1)) ? 1 : 0;
    }
    __syncthreads();
    if (!last_s) return;

    // ---- last-block fused finish (agent-scope loads bypass stale caches) ---
    // total = sum_k [ s2sum_k/(c_k*D*K) - sum_col S1[k,col]^2/(c_k^2*D*K) ]
    float part = 0.f;
#pragma unroll
    for (int k = 0; k < K_CLS; ++k) {
        const float c = (float)counts[k];
        const float inv2 = 1.0f / (c * c * (float)D_DIM * (float)K_CLS);
        const float* Sk = S1 + k * D_DIM;
        for (int j = 0; j < D_DIM / 256; ++j) {    // 24 coalesced agent loads
            float vv = load_dev(&Sk[j * 256 + tid]);
            part -= vv * vv * inv2;
        }
        if (tid == 0)
            part += load_dev(&s2sum[k]) / (c * (float)D_DIM * (float)K_CLS);
    }
    float r = wave_sum(part);
    if (lane == 0) wred[wid] = r;
    __syncthreads();
    if (tid == 0) *out = wred[0] + wred[1] + wred[2] + wred[3];
}

extern "C" void kernel_launch(void* const* d_in, const int* in_sizes, int n_in,
                              void* d_out, int out_size, void* d_ws, size_t ws_size,
                              hipStream_t stream) {
    const float* X = (const float*)d_in[0];
    const int* y = (const int*)d_in[1];

    float* S1 = (float*)d_ws;                       // K*D floats
    float* s2sum = S1 + K_CLS * D_DIM;              // K floats
    int* counts = (int*)(s2sum + K_CLS);            // K ints
    int* sorted = counts + K_CLS;                   // N ints
    unsigned* ctr = (unsigned*)(sorted + N_SAMP);   // 1 uint (arrival ticket)
    float* out = (float*)d_out;

    // 2 dispatches total.
    build_sort<<<dim3(1), dim3(1024), 0, stream>>>(y, counts, sorted,
                                                   S1, s2sum, ctr);
    wcss_accum<<<dim3(NGROUPS, NWIN), dim3(256), 0, stream>>>(X, sorted, counts,
                                                              S1, s2sum, ctr, out);
}

// Round 6
// 324.313 us; speedup vs baseline: 1.0375x; 1.0255x over previous
//
#include <hip/hip_runtime.h>

#define N_SAMP 8192
#define D_DIM 6144
#define K_CLS 10
#define RWIN 256                      // rows per window (>= no 2 boundaries)
#define NWIN2 (N_SAMP / RWIN)         // 32 windows
#define CG 24                         // column groups of 256 cols
#define TPB 64                        // ONE wave per block
#define NBLK (CG * NWIN2)             // 768 = exactly 3 blocks/CU

typedef float f4 __attribute__((ext_vector_type(4)));

// Device-scope (agent) relaxed atomics: execute at the device coherence point;
// never dirty a per-XCD L2, no fences needed (r1 lesson: agent fences =
// buffer_wbl2/inv = 3.5x). r4 lesson: the atomic FLUSH VOLUME itself
// (1.6M f32 RMWs, WRITE_SIZE 25.7MB for a 240KB output) was the bottleneck,
// not load pipelining -> this version cuts flush floats 7.4x structurally.
__device__ __forceinline__ void atom_add_dev(float* p, float v) {
    __hip_atomic_fetch_add(p, v, __ATOMIC_RELAXED, __HIP_MEMORY_SCOPE_AGENT);
}
__device__ __forceinline__ float load_dev(const float* p) {
    return __hip_atomic_load(p, __ATOMIC_RELAXED, __HIP_MEMORY_SCOPE_AGENT);
}
__device__ __forceinline__ float wave_sum(float x) {
#pragma unroll
    for (int o = 32; o > 0; o >>= 1) x += __shfl_down(x, o, 64);
    return x;
}

// Kernel A: 1024-thread atomic-free counting sort by class, fused zero-init of
// S1/s2sum/ctr, plus per-window metadata {bpos, kA, kB} derived from class
// starts (window w rows [w*256,(w+1)*256) in sorted order contain at most ONE
// class boundary since min class count >> 256).
__global__ __launch_bounds__(1024) void build_sort(const int* __restrict__ y,
                                                   int* __restrict__ counts,
                                                   int* __restrict__ sorted,
                                                   float* __restrict__ S1,
                                                   float* __restrict__ s2sum,
                                                   unsigned* __restrict__ ctr,
                                                   int4* __restrict__ win_meta) {
    __shared__ int M[K_CLS * 1024];
    __shared__ int wsum[16];
    __shared__ int cls_start[K_CLS + 1];
    const int tid = threadIdx.x;
    const int lane = tid & 63;
    const int wid = tid >> 6;

    // ---- fused zero-init: S1 (61440 f) + s2sum (10 f) + arrival ctr ----
    {
        f4 z = {0.f, 0.f, 0.f, 0.f};
        f4* p = (f4*)S1;
#pragma unroll
        for (int i = 0; i < (K_CLS * D_DIM) / (4 * 1024); ++i)  // 15 per thread
            p[i * 1024 + tid] = z;
        if (tid < K_CLS) s2sum[tid] = 0.f;
        if (tid == K_CLS) *ctr = 0u;
    }

    // per-thread histogram over 8 contiguous labels (int4 loads)
    const int base = tid * 8;
    const int4 ya = ((const int4*)y)[tid * 2];
    const int4 yb = ((const int4*)y)[tid * 2 + 1];
    int yy[8] = {ya.x, ya.y, ya.z, ya.w, yb.x, yb.y, yb.z, yb.w};
    int h[K_CLS];
#pragma unroll
    for (int k = 0; k < K_CLS; ++k) h[k] = 0;
#pragma unroll
    for (int i = 0; i < 8; ++i)
#pragma unroll
        for (int k = 0; k < K_CLS; ++k) h[k] += (yy[i] == k) ? 1 : 0;
#pragma unroll
    for (int k = 0; k < K_CLS; ++k) M[k * 1024 + tid] = h[k];
    __syncthreads();

    // block exclusive scan over M flat [10240]
    int loc[K_CLS];
    int run = 0;
#pragma unroll
    for (int j = 0; j < K_CLS; ++j) { loc[j] = run; run += M[tid * K_CLS + j]; }
    int v = run;
#pragma unroll
    for (int d = 1; d < 64; d <<= 1) {
        int n = __shfl_up(v, d, 64);
        if (lane >= d) v += n;
    }
    if (lane == 63) wsum[wid] = v;
    __syncthreads();
    int wbase = 0;
#pragma unroll
    for (int w = 0; w < 16; ++w) wbase += (w < wid) ? wsum[w] : 0;
    const int tbase = wbase + (v - run);
    __syncthreads();
#pragma unroll
    for (int j = 0; j < K_CLS; ++j) M[tid * K_CLS + j] = tbase + loc[j];
    __syncthreads();

    if (tid < K_CLS) {
        const int s = M[tid * 1024];
        const int e = (tid == K_CLS - 1) ? N_SAMP : M[(tid + 1) * 1024];
        counts[tid] = e - s;
        cls_start[tid] = s;
        if (tid == 0) cls_start[K_CLS] = N_SAMP;
    }
    __syncthreads();

    // per-window metadata from class starts (pure arithmetic, no re-read)
    if (tid < NWIN2) {
        const int lo = tid * RWIN, hi = lo + RWIN;
        int kA = 0;
#pragma unroll
        for (int k = 0; k < K_CLS; ++k)
            if (cls_start[k] <= lo) kA = k;
        const int bnd = cls_start[kA + 1];
        const int bpos = (bnd < hi) ? (bnd - lo) : RWIN;   // in [1, RWIN]
        const int kB = (bpos < RWIN) ? (kA + 1) : kA;
        win_meta[tid] = make_int4(bpos, kA, kB, 0);
    }

    // stable scatter, class packed in high bits (M untouched since scan)
    int off[K_CLS];
#pragma unroll
    for (int k = 0; k < K_CLS; ++k) off[k] = M[k * 1024 + tid];
#pragma unroll
    for (int i = 0; i < 8; ++i)
#pragma unroll
        for (int k = 0; k < K_CLS; ++k)
            if (yy[i] == k) sorted[off[k]++] = (k << 16) | (base + i);
}

// Kernel B: one block = ONE wave = one 256-row sorted window x 256-col slice.
// Class is uniform per segment (<=2 segments/window) -> branch-free inner
// loop, exactly ONE S1 flush per segment: flush volume 1.57M -> ~212K floats
// (the r4-diagnosed bottleneck). All 24 col-blocks of a window co-dispatch ->
// each 24KB row read in full, clustered in time (DRAM-friendly gather).
__global__ __launch_bounds__(TPB) void wcss_accum(const float* __restrict__ X,
                                                  const int* __restrict__ sorted,
                                                  const int4* __restrict__ win_meta,
                                                  const int* __restrict__ counts,
                                                  float* __restrict__ S1,
                                                  float* __restrict__ s2sum,
                                                  unsigned* __restrict__ ctr,
                                                  float* __restrict__ out) {
    __shared__ int off_lds[RWIN];     // row byte-offsets for this window
    const int tid = threadIdx.x;      // 0..63 == lane
    const int wy = blockIdx.y;
    const int col0 = blockIdx.x * (TPB * 4) + tid * 4;

    // prologue: 256 packed entries -> byte offsets in LDS (one int4/thread)
    {
        const int4 pp = ((const int4*)(sorted + wy * RWIN))[tid];
        off_lds[tid * 4 + 0] = (pp.x & 0xffff) * (D_DIM * 4);
        off_lds[tid * 4 + 1] = (pp.y & 0xffff) * (D_DIM * 4);
        off_lds[tid * 4 + 2] = (pp.z & 0xffff) * (D_DIM * 4);
        off_lds[tid * 4 + 3] = (pp.w & 0xffff) * (D_DIM * 4);
    }
    // cross-lane LDS dependency inside one wave: pin ordering (compiler could
    // otherwise hoist a ds_read above the ds_writes -- r5 hardening fix).
    __syncthreads();

    const int4 meta = win_meta[wy];
    const int bpos = __builtin_amdgcn_readfirstlane(meta.x);
    const int kA   = __builtin_amdgcn_readfirstlane(meta.y);
    const int kB   = __builtin_amdgcn_readfirstlane(meta.z);

    const char* xb = (const char*)X + (size_t)col0 * 4;

    // scalar row offset (broadcast ds_read + readfirstlane) -> saddr-form load
#define LOADR(r) (*(const f4*)(xb + (size_t)(unsigned) \
        __builtin_amdgcn_readfirstlane(off_lds[(r)])))
#define CONSUME(V) { a1 += (V); \
        s2c += (V).x*(V).x + (V).y*(V).y + (V).z*(V).z + (V).w*(V).w; }

    f4 a1; float s2c; int r;
#define SEG(sBeg, sEnd, KC)                                                  \
    {                                                                        \
        a1 = (f4){0.f, 0.f, 0.f, 0.f}; s2c = 0.f;                            \
        r = (sBeg);                                                          \
        for (; r + 8 <= (sEnd); r += 8) {  /* branch-free chunk of 8 */      \
            f4 v0 = LOADR(r+0), v1 = LOADR(r+1), v2 = LOADR(r+2),            \
               v3 = LOADR(r+3), v4 = LOADR(r+4), v5 = LOADR(r+5),            \
               v6 = LOADR(r+6), v7 = LOADR(r+7);                             \
            asm volatile("" :: "v"(v0), "v"(v1), "v"(v2), "v"(v3),           \
                               "v"(v4), "v"(v5), "v"(v6), "v"(v7));          \
            CONSUME(v0) CONSUME(v1) CONSUME(v2) CONSUME(v3)                  \
            CONSUME(v4) CONSUME(v5) CONSUME(v6) CONSUME(v7)                  \
        }                                                                    \
        for (; r < (sEnd); ++r) { f4 vv = LOADR(r); CONSUME(vv) }            \
        float* p1 = S1 + (KC) * D_DIM + col0;                                \
        atom_add_dev(p1 + 0, a1.x); atom_add_dev(p1 + 1, a1.y);              \
        atom_add_dev(p1 + 2, a1.z); atom_add_dev(p1 + 3, a1.w);              \
        float rs_ = wave_sum(s2c);                                           \
        if (tid == 0) atom_add_dev(&s2sum[(KC)], rs_);                       \
    }

    SEG(0, bpos, kA)
    if (bpos < RWIN) { SEG(bpos, RWIN, kB) }
#undef SEG
#undef CONSUME
#undef LOADR

    // single wave: my device-scope atomics complete, then take a ticket
    asm volatile("s_waitcnt vmcnt(0)" ::: "memory");
    unsigned t = 0;
    if (tid == 0)
        t = __hip_atomic_fetch_add(ctr, 1u, __ATOMIC_RELAXED,
                                   __HIP_MEMORY_SCOPE_AGENT);
    t = __shfl((int)t, 0, 64);
    if (t != (unsigned)(NBLK - 1)) return;

    // ---- last-block fused finish (agent-scope loads bypass stale caches) ---
    // total = sum_k [ s2sum_k/(c_k*D*K) - sum_col S1[k,col]^2/(c_k^2*D*K) ]
    float part = 0.f;
#pragma unroll
    for (int k = 0; k < K_CLS; ++k) {
        const float c = (float)counts[k];
        const float inv2 = 1.0f / (c * c * (float)D_DIM * (float)K_CLS);
        const float* Sk = S1 + k * D_DIM;
        for (int j = 0; j < D_DIM / TPB; ++j) {
            float vv = load_dev(&Sk[j * TPB + tid]);
            part -= vv * vv * inv2;
        }
        if (tid == 0)
            part += load_dev(&s2sum[k]) / (c * (float)D_DIM * (float)K_CLS);
    }
    float rr = wave_sum(part);
    if (tid == 0) *out = rr;
}

extern "C" void kernel_launch(void* const* d_in, const int* in_sizes, int n_in,
                              void* d_out, int out_size, void* d_ws, size_t ws_size,
                              hipStream_t stream) {
    const float* X = (const float*)d_in[0];
    const int* y = (const int*)d_in[1];

    float* S1 = (float*)d_ws;                        // 61440 f
    float* s2sum = S1 + K_CLS * D_DIM;               // 10 f
    int* counts = (int*)(s2sum + K_CLS);             // 10 i
    unsigned* ctr = (unsigned*)(counts + K_CLS);     // 1 u
    // pad to 16B for int4
    char* p = (char*)(ctr + 1);
    p += (16 - ((uintptr_t)p & 15)) & 15;
    int4* win_meta = (int4*)p;                       // 32 int4
    int* sorted = (int*)(win_meta + NWIN2);          // 8192 i
    float* out = (float*)d_out;

    // 2 dispatches total.
    build_sort<<<dim3(1), dim3(1024), 0, stream>>>(y, counts, sorted,
                                                   S1, s2sum, ctr, win_meta);
    wcss_accum<<<dim3(CG, NWIN2), dim3(TPB), 0, stream>>>(X, sorted, win_meta,
                                                          counts, S1, s2sum,
                                                          ctr, out);
}

// Round 7
// 298.890 us; speedup vs baseline: 1.1257x; 1.0851x over previous
//
#include <hip/hip_runtime.h>

#define N_SAMP 8192
#define D_DIM 6144
#define K_CLS 10
#define RWIN 256                      // rows per window (max ONE class boundary)
#define NWIN2 (N_SAMP / RWIN)         // 32 windows
#define CGW 24                        // col groups of 256 cols for accum
#define TPB 256                       // 4 waves: waves split the window rows
#define RPW 64                        // rows per wave
#define FIN_COLS 1024
#define FIN_G (D_DIM / FIN_COLS)      // 6 -> finish grid 60 blocks

typedef float f4 __attribute__((ext_vector_type(4)));

// Device-scope (agent) relaxed atomics: execute at the device coherence point;
// never dirty a per-XCD L2, no fences needed (r1: agent fences = wbl2/inv =
// 3.5x). r6 lesson: the last-block single-wave fused finish was a 60-90us
// SERIAL TAIL (960 agent-scope loads on one wave) -> finish is a separate
// parallel kernel again; accum gets 4 waves/block for TLP.
__device__ __forceinline__ void atom_add_dev(float* p, float v) {
    __hip_atomic_fetch_add(p, v, __ATOMIC_RELAXED, __HIP_MEMORY_SCOPE_AGENT);
}
__device__ __forceinline__ float wave_sum(float x) {
#pragma unroll
    for (int o = 32; o > 0; o >>= 1) x += __shfl_down(x, o, 64);
    return x;
}

// Kernel A: 1024-thread atomic-free counting sort by class, fused zero-init of
// S1/s2sum/out, plus per-window metadata {bpos,kA,kB} from class starts
// (window rows [w*256,(w+1)*256) in sorted order hold at most ONE boundary).
__global__ __launch_bounds__(1024) void build_sort(const int* __restrict__ y,
                                                   int* __restrict__ counts,
                                                   int* __restrict__ sorted,
                                                   float* __restrict__ S1,
                                                   float* __restrict__ s2sum,
                                                   int4* __restrict__ win_meta,
                                                   float* __restrict__ out) {
    __shared__ int M[K_CLS * 1024];
    __shared__ int wsum[16];
    __shared__ int cls_start[K_CLS + 1];
    const int tid = threadIdx.x;
    const int lane = tid & 63;
    const int wid = tid >> 6;

    // ---- fused zero-init: S1 (61440 f) + s2sum (10 f) + out ----
    {
        f4 z = {0.f, 0.f, 0.f, 0.f};
        f4* p = (f4*)S1;
#pragma unroll
        for (int i = 0; i < (K_CLS * D_DIM) / (4 * 1024); ++i)  // 15 per thread
            p[i * 1024 + tid] = z;
        if (tid < K_CLS) s2sum[tid] = 0.f;
        if (tid == K_CLS) *out = 0.f;
    }

    // per-thread histogram over 8 contiguous labels (int4 loads)
    const int base = tid * 8;
    const int4 ya = ((const int4*)y)[tid * 2];
    const int4 yb = ((const int4*)y)[tid * 2 + 1];
    int yy[8] = {ya.x, ya.y, ya.z, ya.w, yb.x, yb.y, yb.z, yb.w};
    int h[K_CLS];
#pragma unroll
    for (int k = 0; k < K_CLS; ++k) h[k] = 0;
#pragma unroll
    for (int i = 0; i < 8; ++i)
#pragma unroll
        for (int k = 0; k < K_CLS; ++k) h[k] += (yy[i] == k) ? 1 : 0;
#pragma unroll
    for (int k = 0; k < K_CLS; ++k) M[k * 1024 + tid] = h[k];
    __syncthreads();

    // block exclusive scan over M flat [10240]
    int loc[K_CLS];
    int run = 0;
#pragma unroll
    for (int j = 0; j < K_CLS; ++j) { loc[j] = run; run += M[tid * K_CLS + j]; }
    int v = run;
#pragma unroll
    for (int d = 1; d < 64; d <<= 1) {
        int n = __shfl_up(v, d, 64);
        if (lane >= d) v += n;
    }
    if (lane == 63) wsum[wid] = v;
    __syncthreads();
    int wbase = 0;
#pragma unroll
    for (int w = 0; w < 16; ++w) wbase += (w < wid) ? wsum[w] : 0;
    const int tbase = wbase + (v - run);
    __syncthreads();
#pragma unroll
    for (int j = 0; j < K_CLS; ++j) M[tid * K_CLS + j] = tbase + loc[j];
    __syncthreads();

    if (tid < K_CLS) {
        const int s = M[tid * 1024];
        const int e = (tid == K_CLS - 1) ? N_SAMP : M[(tid + 1) * 1024];
        counts[tid] = e - s;
        cls_start[tid] = s;
        if (tid == 0) cls_start[K_CLS] = N_SAMP;
    }
    __syncthreads();

    // per-window metadata from class starts (pure arithmetic)
    if (tid < NWIN2) {
        const int lo = tid * RWIN, hi = lo + RWIN;
        int kA = 0;
#pragma unroll
        for (int k = 0; k < K_CLS; ++k)
            if (cls_start[k] <= lo) kA = k;
        const int bnd = cls_start[kA + 1];
        const int bpos = (bnd < hi) ? (bnd - lo) : RWIN;   // in [1, RWIN]
        const int kB = (bpos < RWIN) ? (kA + 1) : kA;
        win_meta[tid] = make_int4(bpos, kA, kB, 0);
    }

    // stable scatter, class packed in high bits
    int off[K_CLS];
#pragma unroll
    for (int k = 0; k < K_CLS; ++k) off[k] = M[k * 1024 + tid];
#pragma unroll
    for (int i = 0; i < 8; ++i)
#pragma unroll
        for (int k = 0; k < K_CLS; ++k)
            if (yy[i] == k) sorted[off[k]++] = (k << 16) | (base + i);
}

// Kernel B: one block = 4 waves x one 256-row sorted window x 256-col slice.
// Waves split rows (64 each), accumulate privately in registers (branch-free
// per segment; class uniform per segment), LDS-combine across waves, then ONE
// atomic flush per class segment per block (flush volume ~212K floats total).
// 768 blocks x 4 waves = 12 waves/CU for latency hiding (r6 had only 3/CU).
__global__ __launch_bounds__(TPB, 4) void wcss_accum(const float* __restrict__ X,
                                                     const int* __restrict__ sorted,
                                                     const int4* __restrict__ win_meta,
                                                     float* __restrict__ S1,
                                                     float* __restrict__ s2sum) {
    __shared__ int off_lds[RWIN];     // row byte-offsets for this window
    __shared__ f4 redA[4][64];
    __shared__ f4 redB[4][64];
    __shared__ float s2red[8];
    const int tid = threadIdx.x;
    const int lane = tid & 63;
    const int wid = tid >> 6;
    const int wy = blockIdx.y;
    const int col0 = blockIdx.x * 256 + lane * 4;

    off_lds[tid] = (sorted[wy * RWIN + tid] & 0xffff) * (D_DIM * 4);
    __syncthreads();

    const int4 meta = win_meta[wy];
    const int bpos = __builtin_amdgcn_readfirstlane(meta.x);
    const int kA   = __builtin_amdgcn_readfirstlane(meta.y);
    const int kB   = __builtin_amdgcn_readfirstlane(meta.z);
    const int wbeg = wid * RPW;
    const int wend = wbeg + RPW;

    const char* xb = (const char*)X + (size_t)col0 * 4;

#define LOADR(r) (*(const f4*)(xb + (size_t)(unsigned) \
        __builtin_amdgcn_readfirstlane(off_lds[(r)])))
#define CONSUME(ACC, S2, V) { ACC += (V); \
        S2 += (V).x*(V).x + (V).y*(V).y + (V).z*(V).z + (V).w*(V).w; }
#define SEGLOOP(sBeg, sEnd, ACC, S2)                                         \
    {                                                                        \
        int r = (sBeg);                                                      \
        for (; r + 8 <= (sEnd); r += 8) {  /* 8 loads in flight */           \
            f4 v0 = LOADR(r+0), v1 = LOADR(r+1), v2 = LOADR(r+2),            \
               v3 = LOADR(r+3), v4 = LOADR(r+4), v5 = LOADR(r+5),            \
               v6 = LOADR(r+6), v7 = LOADR(r+7);                             \
            asm volatile("" :: "v"(v0), "v"(v1), "v"(v2), "v"(v3),           \
                               "v"(v4), "v"(v5), "v"(v6), "v"(v7));          \
            CONSUME(ACC, S2, v0) CONSUME(ACC, S2, v1)                        \
            CONSUME(ACC, S2, v2) CONSUME(ACC, S2, v3)                        \
            CONSUME(ACC, S2, v4) CONSUME(ACC, S2, v5)                        \
            CONSUME(ACC, S2, v6) CONSUME(ACC, S2, v7)                        \
        }                                                                    \
        for (; r < (sEnd); ++r) { f4 vv = LOADR(r); CONSUME(ACC, S2, vv) }   \
    }

    f4 aA = {0.f, 0.f, 0.f, 0.f}, aB = {0.f, 0.f, 0.f, 0.f};
    float s2A = 0.f, s2B = 0.f;

    // this wave's slice of segment A ([0,bpos) class kA):
    { const int aEnd = (bpos < wend) ? bpos : wend;
      if (aEnd > wbeg) SEGLOOP(wbeg, aEnd, aA, s2A) }
    // this wave's slice of segment B ([bpos,RWIN) class kB):
    { const int bBeg = (bpos > wbeg) ? bpos : wbeg;
      if (bBeg < wend) SEGLOOP(bBeg, wend, aB, s2B) }
#undef SEGLOOP
#undef CONSUME
#undef LOADR

    // cross-wave combine in LDS, then ONE flush per segment per block
    redA[wid][lane] = aA;
    redB[wid][lane] = aB;
    const float rA = wave_sum(s2A);
    const float rB = wave_sum(s2B);
    if (lane == 0) { s2red[wid] = rA; s2red[4 + wid] = rB; }
    __syncthreads();

    if (wid == 0) {
        const f4 s = redA[0][lane] + redA[1][lane] + redA[2][lane] + redA[3][lane];
        float* p1 = S1 + kA * D_DIM + col0;
        atom_add_dev(p1 + 0, s.x); atom_add_dev(p1 + 1, s.y);
        atom_add_dev(p1 + 2, s.z); atom_add_dev(p1 + 3, s.w);
        if (lane == 0)
            atom_add_dev(&s2sum[kA], s2red[0] + s2red[1] + s2red[2] + s2red[3]);
    } else if (wid == 1 && bpos < RWIN) {
        const f4 s = redB[0][lane] + redB[1][lane] + redB[2][lane] + redB[3][lane];
        float* p1 = S1 + kB * D_DIM + col0;
        atom_add_dev(p1 + 0, s.x); atom_add_dev(p1 + 1, s.y);
        atom_add_dev(p1 + 2, s.z); atom_add_dev(p1 + 3, s.w);
        if (lane == 0)
            atom_add_dev(&s2sum[kB], s2red[4] + s2red[5] + s2red[6] + s2red[7]);
    }
}

// Kernel C: parallel finish, 60 blocks x 256 threads (r0-proven pattern;
// same-stream kernel boundary makes the device-scope atomics visible).
// Per cell add -S1^2/(cnt^2*D*K); one thread also adds s2sum_k/(cnt*D*K).
__global__ __launch_bounds__(256) void wcss_finish(const float* __restrict__ S1,
                                                   const float* __restrict__ s2sum,
                                                   const int* __restrict__ counts,
                                                   float* __restrict__ out) {
    __shared__ float sbuf[256];
    const int tid = threadIdx.x;
    const int k = blockIdx.x / FIN_G;
    const int g = blockIdx.x % FIN_G;
    const float cnt = (float)counts[k];
    const float inv = 1.0f / (cnt * cnt * (float)D_DIM * (float)K_CLS);

    const f4 v = *(const f4*)(S1 + k * D_DIM + g * FIN_COLS + tid * 4);
    float t = -(v.x * v.x + v.y * v.y + v.z * v.z + v.w * v.w) * inv;
    if (g == 0 && tid == 0)
        t += s2sum[k] / (cnt * (float)D_DIM * (float)K_CLS);

    sbuf[tid] = t;
    __syncthreads();
    for (int off = 128; off > 0; off >>= 1) {
        if (tid < off) sbuf[tid] += sbuf[tid + off];
        __syncthreads();
    }
    if (tid == 0) atomicAdd(out, sbuf[0]);
}

extern "C" void kernel_launch(void* const* d_in, const int* in_sizes, int n_in,
                              void* d_out, int out_size, void* d_ws, size_t ws_size,
                              hipStream_t stream) {
    const float* X = (const float*)d_in[0];
    const int* y = (const int*)d_in[1];

    float* S1 = (float*)d_ws;                        // 61440 f
    float* s2sum = S1 + K_CLS * D_DIM;               // 10 f
    int* counts = (int*)(s2sum + K_CLS);             // 10 i
    // pad to 16B for int4
    char* p = (char*)(counts + K_CLS);
    p += (16 - ((uintptr_t)p & 15)) & 15;
    int4* win_meta = (int4*)p;                       // 32 int4
    int* sorted = (int*)(win_meta + NWIN2);          // 8192 i
    float* out = (float*)d_out;

    // 3 dispatches (separate parallel finish: r6's fused single-wave finish
    // was a 60-90us serial tail; a dispatch boundary costs ~1us).
    build_sort<<<dim3(1), dim3(1024), 0, stream>>>(y, counts, sorted,
                                                   S1, s2sum, win_meta, out);
    wcss_accum<<<dim3(CGW, NWIN2), dim3(TPB), 0, stream>>>(X, sorted, win_meta,
                                                           S1, s2sum);
    wcss_finish<<<dim3(K_CLS * FIN_G), dim3(256), 0, stream>>>(S1, s2sum,
                                                               counts, out);
}